// Round 1
// baseline (252.907 us; speedup 1.0000x reference)
//
#include <hip/hip_runtime.h>

// GE2E loss: N=1024 speakers, M=32 utts, D=512.
// loss = mean(1 - sigmoid(w*ex+b) + max_other(sigmoid(w*sims+b)))
// acc  = mean(argmax(sims_row) == spk)
// sims = e @ ck.T  (bf16 MFMA), diag replaced by exclusive centroid via
// identity ex = (m*(e.ck_own) - ||e||^2)/(m-1), ||e||^2 == 1 (normed input).

#define N_SPK 1024
#define M_UTT 32
#define D_DIM 512
#define NROWS (N_SPK * M_UTT)   // 32768
#define ROWS_PER_WG 64
#define NWG (NROWS / ROWS_PER_WG) // 512

typedef __attribute__((ext_vector_type(8))) short short8v;  // 8 bf16 (4 VGPR)
typedef __attribute__((ext_vector_type(4))) float f32x4;

__device__ __forceinline__ unsigned short f2bf(float f) {
    union { float f; unsigned int u; } v; v.f = f;
    unsigned int u = v.u;
    u += 0x7fffu + ((u >> 16) & 1u);   // RNE
    return (unsigned short)(u >> 16);
}

// ---------------- kernel 1: ck_bf16[n][d] = bf16(mean_m emb[n][m][d]) -------
__global__ void __launch_bounds__(256) ck_kernel(const float* __restrict__ emb,
                                                 unsigned short* __restrict__ ck) {
    int n = blockIdx.x;
    int t = threadIdx.x;
    const float* base = emb + (size_t)n * M_UTT * D_DIM;
#pragma unroll
    for (int h = 0; h < 2; ++h) {
        int d = h * 256 + t;
        float s = 0.f;
#pragma unroll
        for (int mm = 0; mm < M_UTT; ++mm) s += base[mm * D_DIM + d];
        ck[(size_t)n * D_DIM + d] = f2bf(s * (1.f / 32.f));
    }
}

// ---------------- kernel 2: fused GEMM + sigmoid + row max/argmax -----------
__global__ void __launch_bounds__(256) main_kernel(const float* __restrict__ emb,
                                                   const unsigned short* __restrict__ ck,
                                                   const float* __restrict__ lnw,
                                                   const float* __restrict__ lnb,
                                                   float* __restrict__ part) {
    __shared__ __align__(16) unsigned short Atile[ROWS_PER_WG * D_DIM]; // 64 KB
    __shared__ float rloss[ROWS_PER_WG];
    __shared__ float rcorr[ROWS_PER_WG];
    char* Ab = (char*)Atile;

    const int tid  = threadIdx.x;
    const int lane = tid & 63;
    const int wave = tid >> 6;
    const int lo   = lane & 15;
    const int hi   = lane >> 4;
    const int r0   = blockIdx.x * ROWS_PER_WG;

    // ---- stage A: 64 rows x 512 f32 -> bf16 LDS, XOR-swizzled ----
    // chunks of 4 floats (16B load -> 8B LDS write); 8192 chunks / 256 thr = 32
#pragma unroll 4
    for (int i = 0; i < 32; ++i) {
        int c   = tid + 256 * i;
        int row = c >> 7;            // 128 chunks per row
        int k4  = (c & 127) * 4;
        const float4 v = *reinterpret_cast<const float4*>(
            emb + (size_t)(r0 + row) * D_DIM + k4);
        ushort4 b;
        b.x = f2bf(v.x); b.y = f2bf(v.y); b.z = f2bf(v.z); b.w = f2bf(v.w);
        int byte = (row * 1024 + k4 * 2) ^ ((row & 7) << 4);
        *reinterpret_cast<ushort4*>(Ab + byte) = b;
    }
    __syncthreads();

    const float lw = lnw[0];
    const float lb = lnb[0];

    const int rowbase = r0 + wave * 16;          // this wave owns rows rowbase..+15
    const int arow    = wave * 16 + lo;          // LDS row for A fragment
    const int aswz    = (arow & 7) << 4;
    const int abase   = arow * 1024 + hi * 16;   // + kk*64, then ^aswz

    float maxo[4], bestv[4], own[4];
    int   besti[4];
#pragma unroll
    for (int r = 0; r < 4; ++r) {
        maxo[r] = -1e30f; bestv[r] = -1e30f; own[r] = -1e30f; besti[r] = 0;
    }

    for (int jg = 0; jg < 16; ++jg) {            // 64-col groups
        f32x4 acc[4];
#pragma unroll
        for (int j = 0; j < 4; ++j) acc[j] = (f32x4){0.f, 0.f, 0.f, 0.f};

        const unsigned short* bcol[4];
#pragma unroll
        for (int j = 0; j < 4; ++j) {
            int col = jg * 64 + j * 16 + lo;
            bcol[j] = ck + (size_t)col * D_DIM + hi * 8;
        }

#pragma unroll 4
        for (int kk = 0; kk < 16; ++kk) {
            short8v a = *reinterpret_cast<const short8v*>(
                Ab + ((abase + kk * 64) ^ aswz));
            short8v b0 = *reinterpret_cast<const short8v*>(bcol[0] + kk * 32);
            short8v b1 = *reinterpret_cast<const short8v*>(bcol[1] + kk * 32);
            short8v b2 = *reinterpret_cast<const short8v*>(bcol[2] + kk * 32);
            short8v b3 = *reinterpret_cast<const short8v*>(bcol[3] + kk * 32);
            acc[0] = __builtin_amdgcn_mfma_f32_16x16x32_bf16(a, b0, acc[0], 0, 0, 0);
            acc[1] = __builtin_amdgcn_mfma_f32_16x16x32_bf16(a, b1, acc[1], 0, 0, 0);
            acc[2] = __builtin_amdgcn_mfma_f32_16x16x32_bf16(a, b2, acc[2], 0, 0, 0);
            acc[3] = __builtin_amdgcn_mfma_f32_16x16x32_bf16(a, b3, acc[3], 0, 0, 0);
        }

        // epilogue for this 64-col group
#pragma unroll
        for (int j = 0; j < 4; ++j) {
            int col = jg * 64 + j * 16 + lo;
#pragma unroll
            for (int reg = 0; reg < 4; ++reg) {
                int row = rowbase + hi * 4 + reg;
                int spk = row >> 5;              // /32
                float s = acc[j][reg];
                float g;
                if (col == spk) {
                    float ex = (32.f * s - 1.f) * (1.f / 31.f);
                    g = 1.f / (1.f + __expf(-(lw * ex + lb)));
                    own[reg] = g;
                } else {
                    g = 1.f / (1.f + __expf(-(lw * s + lb)));
                    maxo[reg] = fmaxf(maxo[reg], g);
                }
                // argmax over ALL columns (diag uses exclusive value)
                if (g > bestv[reg]) { bestv[reg] = g; besti[reg] = col; }
            }
        }
    }

    // ---- cross-lane (16 lanes share each row) reduce ----
#pragma unroll
    for (int reg = 0; reg < 4; ++reg) {
        float mo = maxo[reg], bv = bestv[reg], ow = own[reg];
        int   bi = besti[reg];
#pragma unroll
        for (int mask = 1; mask < 16; mask <<= 1) {
            float omo = __shfl_xor(mo, mask);
            float obv = __shfl_xor(bv, mask);
            int   obi = __shfl_xor(bi, mask);
            float oow = __shfl_xor(ow, mask);
            mo = fmaxf(mo, omo);
            if (obv > bv || (obv == bv && obi < bi)) { bv = obv; bi = obi; }
            ow = fmaxf(ow, oow);
        }
        if (lo == 0) {
            int lr  = wave * 16 + hi * 4 + reg;
            int row = r0 + lr;
            int spk = row >> 5;
            rloss[lr] = 1.0f - ow + mo;
            rcorr[lr] = (bi == spk) ? 1.0f : 0.0f;
        }
    }
    __syncthreads();

    if (tid < 64) {
        float l = rloss[tid];
        float c = rcorr[tid];
#pragma unroll
        for (int mask = 1; mask < 64; mask <<= 1) {
            l += __shfl_xor(l, mask);
            c += __shfl_xor(c, mask);
        }
        if (tid == 0) {
            part[blockIdx.x]       = l;
            part[NWG + blockIdx.x] = c;
        }
    }
}

// ---------------- kernel 3: final deterministic reduction -------------------
__global__ void __launch_bounds__(256) finish_kernel(const float* __restrict__ part,
                                                     float* __restrict__ out) {
    __shared__ float sl[256];
    __shared__ float sc[256];
    int t = threadIdx.x;
    sl[t] = part[t] + part[t + 256];
    sc[t] = part[NWG + t] + part[NWG + t + 256];
    __syncthreads();
    for (int s = 128; s > 0; s >>= 1) {
        if (t < s) { sl[t] += sl[t + s]; sc[t] += sc[t + s]; }
        __syncthreads();
    }
    if (t == 0) {
        out[0] = sl[0] * (1.f / (float)NROWS);
        out[1] = sc[0] * (1.f / (float)NROWS);
    }
}

extern "C" void kernel_launch(void* const* d_in, const int* in_sizes, int n_in,
                              void* d_out, int out_size, void* d_ws, size_t ws_size,
                              hipStream_t stream) {
    (void)in_sizes; (void)n_in; (void)out_size; (void)ws_size;
    const float* emb = (const float*)d_in[0];
    const float* lnw = (const float*)d_in[3];
    const float* lnb = (const float*)d_in[4];
    float* out = (float*)d_out;

    unsigned short* ck = (unsigned short*)d_ws;                       // 1 MB
    float* part = (float*)((char*)d_ws + (size_t)N_SPK * D_DIM * 2);  // 4 KB

    ck_kernel<<<N_SPK, 256, 0, stream>>>(emb, ck);
    main_kernel<<<NWG, 256, 0, stream>>>(emb, ck, lnw, lnb, part);
    finish_kernel<<<1, 256, 0, stream>>>(part, out);
}

// Round 2
// 79.985 us; speedup vs baseline: 3.1619x; 3.1619x over previous
//
#include <hip/hip_runtime.h>

// GE2E loss, N=1024 spk, M=32 utt, D=512.
// sims = e @ ck.T as bf16 MFMA GEMM (m97-style LDS-staged, 128x128 tile, BK=64),
// diag via ex = (32*(e.ck_own) - 1)/31 (unit-norm rows), sigmoid deferred to
// the per-row finish (monotone => max/argmax computed on raw sims).

#define N_SPK 1024
#define M_UTT 32
#define D_DIM 512
#define NROWS (N_SPK * M_UTT)   // 32768
#define BM 128
#define BN 128
#define BK 64
#define KSTEPS (D_DIM / BK)     // 8
#define NTILES (N_SPK / BN)     // 8
#define MTILES (NROWS / BM)     // 256

typedef __attribute__((ext_vector_type(8))) short short8v;  // 8 bf16
typedef __attribute__((ext_vector_type(4))) float f32x4;

__device__ __forceinline__ unsigned short f2bf(float f) {
    union { float f; unsigned int u; } v; v.f = f;
    unsigned int u = v.u;
    u += 0x7fffu + ((u >> 16) & 1u);   // RNE
    return (unsigned short)(u >> 16);
}

__device__ __forceinline__ void gload_lds16(const void* g, void* l) {
    __builtin_amdgcn_global_load_lds(
        (const __attribute__((address_space(1))) unsigned int*)g,
        (__attribute__((address_space(3))) unsigned int*)l, 16, 0, 0);
}

__device__ __forceinline__ float sigmoidf(float x) {
    return 1.f / (1.f + __expf(-x));
}

// ---- k1: emb fp32 -> ebf bf16 (32 MB) and ck bf16 (scaled by sgn(lw)/32) ----
__global__ void __launch_bounds__(256) prep_kernel(const float* __restrict__ emb,
                                                   const float* __restrict__ lnw,
                                                   unsigned short* __restrict__ ebf,
                                                   unsigned short* __restrict__ ck) {
    __shared__ float part[2][D_DIM];
    const int n = blockIdx.x;
    const int t = threadIdx.x;
    const int d4 = (t & 127) * 4;
    const int mh = t >> 7;
    const float* base = emb + (size_t)n * M_UTT * D_DIM;
    unsigned short* obase = ebf + (size_t)n * M_UTT * D_DIM;

    float4 acc = {0.f, 0.f, 0.f, 0.f};
#pragma unroll
    for (int mm = 0; mm < 16; ++mm) {
        const int m = mh * 16 + mm;
        const float4 v = *reinterpret_cast<const float4*>(base + m * D_DIM + d4);
        acc.x += v.x; acc.y += v.y; acc.z += v.z; acc.w += v.w;
        ushort4 b;
        b.x = f2bf(v.x); b.y = f2bf(v.y); b.z = f2bf(v.z); b.w = f2bf(v.w);
        *reinterpret_cast<ushort4*>(obase + m * D_DIM + d4) = b;
    }
    *reinterpret_cast<float4*>(&part[mh][d4]) = acc;
    __syncthreads();
    if (t < 128) {
        const float sgn = (lnw[0] >= 0.f) ? 1.f : -1.f;
        const float sc = sgn * (1.f / 32.f);
        const int d = t * 4;
        const float4 a = *reinterpret_cast<const float4*>(&part[0][d]);
        const float4 b = *reinterpret_cast<const float4*>(&part[1][d]);
        ushort4 o;
        o.x = f2bf((a.x + b.x) * sc); o.y = f2bf((a.y + b.y) * sc);
        o.z = f2bf((a.z + b.z) * sc); o.w = f2bf((a.w + b.w) * sc);
        *reinterpret_cast<ushort4*>(ck + (size_t)n * D_DIM + d) = o;
    }
}

// ---- k2: GEMM 128x128 tiles + fused per-tile row max / own capture --------
__global__ void __launch_bounds__(256) gemm_kernel(const unsigned short* __restrict__ ebf,
                                                   const unsigned short* __restrict__ ck,
                                                   float* __restrict__ maxo_part,
                                                   float* __restrict__ own_part) {
    __shared__ __align__(16) unsigned short As[BM * BK];  // 16 KB
    __shared__ __align__(16) unsigned short Bs[BN * BK];  // 16 KB
    __shared__ float red[2][BM];
    __shared__ float redown[BM];

    const int tid  = threadIdx.x;
    const int lane = tid & 63;
    const int wv   = tid >> 6;
    const int lo   = lane & 15;
    const int hi   = lane >> 4;
    const int mt   = blockIdx.x >> 3;
    const int nt   = blockIdx.x & 7;
    const int r0   = mt * BM;
    const int n0   = nt * BN;

    // staging: chunk c = (wv*4+j)*64 + lane; row = c>>3; fetch slot = (lane&7)^(row&7)
    const int srow  = lane >> 3;                 // row within group of 8
    const int sslot = (lane & 7) ^ srow;         // pre-swizzled global slot
    const unsigned short* agl[4];
    const unsigned short* bgl[4];
    unsigned short* al[4];
    unsigned short* bl[4];
#pragma unroll
    for (int j = 0; j < 4; ++j) {
        const int rowb = (wv * 4 + j) * 8 + srow;
        agl[j] = ebf + (size_t)(r0 + rowb) * D_DIM + sslot * 8;
        bgl[j] = ck  + (size_t)(n0 + rowb) * D_DIM + sslot * 8;
        al[j]  = As + (wv * 4 + j) * 512;        // wave-uniform, 1 KB chunks
        bl[j]  = Bs + (wv * 4 + j) * 512;
    }

    const int wm = wv >> 1;
    const int wn = wv & 1;
    const int r3 = lo & 7;                       // = mrow&7 = col&7

    f32x4 acc[4][4];
#pragma unroll
    for (int m = 0; m < 4; ++m)
#pragma unroll
        for (int n = 0; n < 4; ++n)
            acc[m][n] = (f32x4){0.f, 0.f, 0.f, 0.f};

    const char* Ab = (const char*)As;
    const char* Bb = (const char*)Bs;

    for (int kt = 0; kt < KSTEPS; ++kt) {
#pragma unroll
        for (int j = 0; j < 4; ++j) gload_lds16(agl[j] + kt * BK, al[j]);
#pragma unroll
        for (int j = 0; j < 4; ++j) gload_lds16(bgl[j] + kt * BK, bl[j]);
        __syncthreads();

        short8v a[4][2], b[4][2];
#pragma unroll
        for (int m = 0; m < 4; ++m) {
            const int mrow = wm * 64 + m * 16 + lo;
#pragma unroll
            for (int kk = 0; kk < 2; ++kk)
                a[m][kk] = *reinterpret_cast<const short8v*>(
                    Ab + mrow * 128 + (((kk * 4 + hi) ^ r3) * 16));
        }
#pragma unroll
        for (int n = 0; n < 4; ++n) {
            const int col = wn * 64 + n * 16 + lo;
#pragma unroll
            for (int kk = 0; kk < 2; ++kk)
                b[n][kk] = *reinterpret_cast<const short8v*>(
                    Bb + col * 128 + (((kk * 4 + hi) ^ r3) * 16));
        }
#pragma unroll
        for (int m = 0; m < 4; ++m)
#pragma unroll
            for (int n = 0; n < 4; ++n) {
                acc[m][n] = __builtin_amdgcn_mfma_f32_16x16x32_bf16(a[m][0], b[n][0], acc[m][n], 0, 0, 0);
                acc[m][n] = __builtin_amdgcn_mfma_f32_16x16x32_bf16(a[m][1], b[n][1], acc[m][n], 0, 0, 0);
            }
        __syncthreads();
    }

    // epilogue: per-lane row maxes (diag excluded) + own capture
    const float NEG = -1e30f;
    float mx[4][4], ow[4][4];
#pragma unroll
    for (int m = 0; m < 4; ++m)
#pragma unroll
        for (int reg = 0; reg < 4; ++reg) { mx[m][reg] = NEG; ow[m][reg] = NEG; }

#pragma unroll
    for (int m = 0; m < 4; ++m)
#pragma unroll
        for (int n = 0; n < 4; ++n) {
            const int col = n0 + wn * 64 + n * 16 + lo;
#pragma unroll
            for (int reg = 0; reg < 4; ++reg) {
                const int row_l = wm * 64 + m * 16 + hi * 4 + reg;
                const int spk   = (r0 + row_l) >> 5;
                const float v   = acc[m][n][reg];
                const bool dg   = (col == spk);
                ow[m][reg] = dg ? v : ow[m][reg];
                mx[m][reg] = fmaxf(mx[m][reg], dg ? NEG : v);
            }
        }

#pragma unroll
    for (int m = 0; m < 4; ++m)
#pragma unroll
        for (int reg = 0; reg < 4; ++reg) {
            float a = mx[m][reg], o = ow[m][reg];
#pragma unroll
            for (int mask = 1; mask < 16; mask <<= 1) {
                a = fmaxf(a, __shfl_xor(a, mask));
                o = fmaxf(o, __shfl_xor(o, mask));
            }
            if (lo == 0) {
                const int rl = wm * 64 + m * 16 + hi * 4 + reg;
                red[wn][rl] = a;
                if (wn == (((r0 >> 5) >> 6) & 1)) redown[rl] = o;
            }
        }
    __syncthreads();

    if (tid < BM) {
        const float mo = fmaxf(red[0][tid], red[1][tid]);
        maxo_part[(size_t)nt * NROWS + r0 + tid] = mo;
        if (nt == (mt >> 5)) own_part[r0 + tid] = redown[tid];
    }
}

// ---- k3: per-row finish: combine 8 tile-maxes, sigmoid, loss/corr ---------
__global__ void __launch_bounds__(256) rowred_kernel(const float* __restrict__ maxo_part,
                                                     const float* __restrict__ own_part,
                                                     const float* __restrict__ lnw,
                                                     const float* __restrict__ lnb,
                                                     float* __restrict__ partsum) {
    const int r = blockIdx.x * 256 + threadIdx.x;
    const float lw = lnw[0], lb = lnb[0];
    const float sgn = (lw >= 0.f) ? 1.f : -1.f;
    const float alw = fabsf(lw);

    float mo = maxo_part[r];
#pragma unroll
    for (int nt2 = 1; nt2 < NTILES; ++nt2)
        mo = fmaxf(mo, maxo_part[(size_t)nt2 * NROWS + r]);
    const float ownp  = own_part[r];          // sgn-scaled raw dot e.ck_own
    const float s_own = sgn * ownp;
    const float ex    = (32.f * s_own - 1.f) * (1.f / 31.f);
    const float own_s = sigmoidf(lw * ex + lb);
    const float mo_s  = sigmoidf(alw * mo + lb);
    float loss = 1.f - own_s + mo_s;
    float corr = (sgn * ex >= mo) ? 1.f : 0.f;

#pragma unroll
    for (int mask = 1; mask < 64; mask <<= 1) {
        loss += __shfl_xor(loss, mask);
        corr += __shfl_xor(corr, mask);
    }
    __shared__ float sl[4], sc[4];
    const int wv = threadIdx.x >> 6;
    if ((threadIdx.x & 63) == 0) { sl[wv] = loss; sc[wv] = corr; }
    __syncthreads();
    if (threadIdx.x == 0) {
        partsum[blockIdx.x]       = sl[0] + sl[1] + sl[2] + sl[3];
        partsum[128 + blockIdx.x] = sc[0] + sc[1] + sc[2] + sc[3];
    }
}

// ---- k4: final scalar reduce ----------------------------------------------
__global__ void __launch_bounds__(128) final_kernel(const float* __restrict__ partsum,
                                                    float* __restrict__ out) {
    const int t = threadIdx.x;
    float l = partsum[t];
    float c = partsum[128 + t];
#pragma unroll
    for (int mask = 1; mask < 64; mask <<= 1) {
        l += __shfl_xor(l, mask);
        c += __shfl_xor(c, mask);
    }
    __shared__ float sl[2], sc[2];
    if ((t & 63) == 0) { sl[t >> 6] = l; sc[t >> 6] = c; }
    __syncthreads();
    if (t == 0) {
        out[0] = (sl[0] + sl[1]) * (1.f / (float)NROWS);
        out[1] = (sc[0] + sc[1]) * (1.f / (float)NROWS);
    }
}

extern "C" void kernel_launch(void* const* d_in, const int* in_sizes, int n_in,
                              void* d_out, int out_size, void* d_ws, size_t ws_size,
                              hipStream_t stream) {
    (void)in_sizes; (void)n_in; (void)out_size; (void)ws_size;
    const float* emb = (const float*)d_in[0];
    const float* lnw = (const float*)d_in[3];
    const float* lnb = (const float*)d_in[4];
    float* out = (float*)d_out;

    char* ws = (char*)d_ws;
    unsigned short* ebf = (unsigned short*)ws;                          // 32 MB
    unsigned short* ck  = (unsigned short*)(ws + (size_t)NROWS * D_DIM * 2);   // 1 MB
    float* maxo_part = (float*)(ws + (size_t)NROWS * D_DIM * 2 + (size_t)N_SPK * D_DIM * 2); // 1 MB
    float* own_part  = (float*)((char*)maxo_part + (size_t)NTILES * NROWS * 4);              // 128 KB
    float* partsum   = (float*)((char*)own_part + (size_t)NROWS * 4);                        // 1 KB

    prep_kernel<<<N_SPK, 256, 0, stream>>>(emb, lnw, ebf, ck);
    gemm_kernel<<<MTILES * NTILES, 256, 0, stream>>>(ebf, ck, maxo_part, own_part);
    rowred_kernel<<<NROWS / 256, 256, 0, stream>>>(maxo_part, own_part, lnw, lnb, partsum);
    final_kernel<<<1, 128, 0, stream>>>(partsum, out);
}

// Round 3
// 74.966 us; speedup vs baseline: 3.3736x; 1.0669x over previous
//
#include <hip/hip_runtime.h>

// GE2E loss, N=1024 spk, M=32 utt, D=512.
// v3: A-resident GEMM. Block = 128 rows x all 1024 cols; A (128x512 bf16,
// 128 KB) converted fp32->bf16 once into LDS; B (ck, 1 MB total) streamed
// via global_load_lds double-buffer (16 KB x2). LDS = 160 KiB exactly.
// Row max / own / loss / acc finished in-block (block owns full rows).

#define N_SPK 1024
#define M_UTT 32
#define D_DIM 512
#define NROWS (N_SPK * M_UTT)   // 32768
#define BM 128
#define NT 8                    // 1024 cols / 128
#define KT 8                    // 512 k / 64
#define GRID (NROWS / BM)       // 256

typedef __attribute__((ext_vector_type(8))) short short8v;  // 8 bf16
typedef __attribute__((ext_vector_type(4))) float f32x4;

__device__ __forceinline__ unsigned short f2bf(float f) {
    union { float f; unsigned int u; } v; v.f = f;
    unsigned int u = v.u;
    u += 0x7fffu + ((u >> 16) & 1u);   // RNE
    return (unsigned short)(u >> 16);
}

__device__ __forceinline__ void gload_lds16(const void* g, void* l) {
    __builtin_amdgcn_global_load_lds(
        (const __attribute__((address_space(1))) unsigned int*)g,
        (__attribute__((address_space(3))) unsigned int*)l, 16, 0, 0);
}

__device__ __forceinline__ float sigmoidf(float x) {
    return 1.f / (1.f + __expf(-x));
}

// ---- k1: ck bf16 (scaled by sgn(lw)/32) from fp32 emb ----------------------
__global__ void __launch_bounds__(256) ck_kernel(const float* __restrict__ emb,
                                                 const float* __restrict__ lnw,
                                                 unsigned short* __restrict__ ck) {
    __shared__ float part[2][D_DIM];
    const int n = blockIdx.x;
    const int t = threadIdx.x;
    const int d4 = (t & 127) * 4;
    const int mh = t >> 7;
    const float* base = emb + (size_t)n * M_UTT * D_DIM;

    float4 acc = {0.f, 0.f, 0.f, 0.f};
#pragma unroll
    for (int mm = 0; mm < 16; ++mm) {
        const int m = mh * 16 + mm;
        const float4 v = *reinterpret_cast<const float4*>(base + m * D_DIM + d4);
        acc.x += v.x; acc.y += v.y; acc.z += v.z; acc.w += v.w;
    }
    *reinterpret_cast<float4*>(&part[mh][d4]) = acc;
    __syncthreads();
    if (t < 128) {
        const float sgn = (lnw[0] >= 0.f) ? 1.f : -1.f;
        const float sc = sgn * (1.f / 32.f);
        const int d = t * 4;
        const float4 a = *reinterpret_cast<const float4*>(&part[0][d]);
        const float4 b = *reinterpret_cast<const float4*>(&part[1][d]);
        ushort4 o;
        o.x = f2bf((a.x + b.x) * sc); o.y = f2bf((a.y + b.y) * sc);
        o.z = f2bf((a.z + b.z) * sc); o.w = f2bf((a.w + b.w) * sc);
        *reinterpret_cast<ushort4*>(ck + (size_t)n * D_DIM + d) = o;
    }
}

// ---- k2: A-resident GEMM + in-block row finish -----------------------------
__global__ void __launch_bounds__(512, 2)
gemm_kernel(const float* __restrict__ emb,
            const unsigned short* __restrict__ ck,
            const float* __restrict__ lnw,
            const float* __restrict__ lnb,
            float* __restrict__ partsum) {
    __shared__ __align__(16) unsigned short As[BM * D_DIM];   // 128 KB
    __shared__ __align__(16) unsigned short Bs[2][128 * 64];  // 2 x 16 KB

    const int tid  = threadIdx.x;
    const int lane = tid & 63;
    const int wv   = tid >> 6;
    const int lo   = lane & 15;
    const int hi   = lane >> 4;
    const int r0   = blockIdx.x * BM;

    const float lw = lnw[0];
    const float lb = lnb[0];

    char* Ab = (char*)As;

    // ---- stage A: 128 rows x 512 fp32 -> bf16 LDS, slot-XOR swizzled ----
    const float* asrc = emb + (size_t)r0 * D_DIM;
#pragma unroll 4
    for (int i = 0; i < 32; ++i) {
        const int c   = tid + 512 * i;
        const int row = c >> 7;              // 128 float4-chunks per row
        const int k4  = (c & 127) * 4;
        const float4 v = *reinterpret_cast<const float4*>(asrc + row * D_DIM + k4);
        ushort4 b;
        b.x = f2bf(v.x); b.y = f2bf(v.y); b.z = f2bf(v.z); b.w = f2bf(v.w);
        const int byte = (row * 1024 + k4 * 2) ^ ((row & 7) << 4);
        *reinterpret_cast<ushort4*>(Ab + byte) = b;
    }

    // ---- B staging geometry (global_load_lds, pre-swizzled source) ----
    // per issue j: col = wv*16 + j*8 + (lane>>3); stored slot = lane&7,
    // source slot = (lane&7) ^ (col&7), col&7 == lane>>3.
    const int bslot = (lane & 7) ^ (lane >> 3);
    const int bcol0 = wv * 16 + (lane >> 3);

    // prologue: tile T=0 (nt=0, kt=0)
    gload_lds16(ck + (size_t)bcol0 * D_DIM + bslot * 8,       &Bs[0][(wv * 2 + 0) * 512]);
    gload_lds16(ck + (size_t)(bcol0 + 8) * D_DIM + bslot * 8, &Bs[0][(wv * 2 + 1) * 512]);
    __syncthreads();

    const int wm = wv >> 2;   // 0..1 : 64-row half
    const int wn = wv & 3;    // 0..3 : 32-col quarter

    const float NEG = -1e30f;
    float mx[4][4], ow[4][4];
#pragma unroll
    for (int m = 0; m < 4; ++m)
#pragma unroll
        for (int r = 0; r < 4; ++r) { mx[m][r] = NEG; ow[m][r] = NEG; }

    for (int nt = 0; nt < NT; ++nt) {
        f32x4 acc[4][2];
#pragma unroll
        for (int m = 0; m < 4; ++m)
#pragma unroll
            for (int n = 0; n < 2; ++n) acc[m][n] = (f32x4){0.f, 0.f, 0.f, 0.f};

        for (int kt = 0; kt < KT; ++kt) {
            const int T = nt * KT + kt;
            if (T < NT * KT - 1) {
                const int T1  = T + 1;
                const int nt2 = T1 >> 3;
                const int kt2 = T1 & 7;
                const unsigned short* s0 =
                    ck + (size_t)(nt2 * 128 + bcol0) * D_DIM + kt2 * 64 + bslot * 8;
                gload_lds16(s0,                     &Bs[T1 & 1][(wv * 2 + 0) * 512]);
                gload_lds16(s0 + (size_t)8 * D_DIM, &Bs[T1 & 1][(wv * 2 + 1) * 512]);
            }
            const char* Bb = (const char*)Bs[T & 1];

            short8v a[4][2], b[2][2];
#pragma unroll
            for (int m = 0; m < 4; ++m) {
                const int arow = wm * 64 + m * 16 + lo;
                const int sw   = arow & 7;
#pragma unroll
                for (int kk = 0; kk < 2; ++kk) {
                    const int slot = (kt * 8 + kk * 4 + hi) ^ sw;
                    a[m][kk] = *reinterpret_cast<const short8v*>(Ab + arow * 1024 + slot * 16);
                }
            }
#pragma unroll
            for (int n = 0; n < 2; ++n) {
                const int col = wn * 32 + n * 16 + lo;
#pragma unroll
                for (int kk = 0; kk < 2; ++kk) {
                    const int slot = (kk * 4 + hi) ^ (col & 7);
                    b[n][kk] = *reinterpret_cast<const short8v*>(Bb + col * 128 + slot * 16);
                }
            }
#pragma unroll
            for (int m = 0; m < 4; ++m)
#pragma unroll
                for (int n = 0; n < 2; ++n) {
                    acc[m][n] = __builtin_amdgcn_mfma_f32_16x16x32_bf16(a[m][0], b[n][0], acc[m][n], 0, 0, 0);
                    acc[m][n] = __builtin_amdgcn_mfma_f32_16x16x32_bf16(a[m][1], b[n][1], acc[m][n], 0, 0, 0);
                }
            __syncthreads();
        }

        // per-nt epilogue: fold acc into running row max / own capture
#pragma unroll
        for (int m = 0; m < 4; ++m)
#pragma unroll
            for (int n = 0; n < 2; ++n) {
                const int col = nt * 128 + wn * 32 + n * 16 + lo;
#pragma unroll
                for (int reg = 0; reg < 4; ++reg) {
                    const int rowg = r0 + wm * 64 + m * 16 + hi * 4 + reg;
                    const int spk  = rowg >> 5;
                    const float v  = acc[m][n][reg];
                    const bool dg  = (col == spk);
                    ow[m][reg] = dg ? v : ow[m][reg];
                    mx[m][reg] = fmaxf(mx[m][reg], dg ? NEG : v);
                }
            }
    }

    // ---- in-block finish: reduce over lo, combine over wn, loss/corr ----
    float* red = (float*)Bs;   // B buffers dead; 8192 floats available
#pragma unroll
    for (int m = 0; m < 4; ++m)
#pragma unroll
        for (int reg = 0; reg < 4; ++reg) {
            float a = mx[m][reg], o = ow[m][reg];
#pragma unroll
            for (int mask = 1; mask < 16; mask <<= 1) {
                a = fmaxf(a, __shfl_xor(a, mask));
                o = fmaxf(o, __shfl_xor(o, mask));
            }
            if (lo == 0) {
                const int rl = wm * 64 + m * 16 + hi * 4 + reg;
                red[wn * 128 + rl]       = a;
                red[512 + wn * 128 + rl] = o;
            }
        }
    __syncthreads();

    if (tid < 128) {
        const float mo = fmaxf(fmaxf(red[tid], red[128 + tid]),
                               fmaxf(red[256 + tid], red[384 + tid]));
        const float op = fmaxf(fmaxf(red[512 + tid], red[640 + tid]),
                               fmaxf(red[768 + tid], red[896 + tid]));
        const float sgn = (lw >= 0.f) ? 1.f : -1.f;
        const float alw = fabsf(lw);
        const float s_own = sgn * op;
        const float ex    = (32.f * s_own - 1.f) * (1.f / 31.f);
        const float own_s = sigmoidf(lw * ex + lb);
        const float mo_s  = sigmoidf(alw * mo + lb);
        float loss = 1.f - own_s + mo_s;
        float corr = (sgn * ex >= mo) ? 1.f : 0.f;
#pragma unroll
        for (int mask = 1; mask < 64; mask <<= 1) {
            loss += __shfl_xor(loss, mask);
            corr += __shfl_xor(corr, mask);
        }
        if ((tid & 63) == 0) {
            red[1024 + (tid >> 6)] = loss;
            red[1026 + (tid >> 6)] = corr;
        }
    }
    __syncthreads();
    if (tid == 0) {
        partsum[blockIdx.x]        = red[1024] + red[1025];
        partsum[GRID + blockIdx.x] = red[1026] + red[1027];
    }
}

// ---- k3: final scalar reduce ----------------------------------------------
__global__ void __launch_bounds__(256) final_kernel(const float* __restrict__ partsum,
                                                    float* __restrict__ out) {
    __shared__ float sl[4], sc[4];
    const int t = threadIdx.x;
    float l = partsum[t];
    float c = partsum[GRID + t];
#pragma unroll
    for (int mask = 1; mask < 64; mask <<= 1) {
        l += __shfl_xor(l, mask);
        c += __shfl_xor(c, mask);
    }
    const int wv = t >> 6;
    if ((t & 63) == 0) { sl[wv] = l; sc[wv] = c; }
    __syncthreads();
    if (t == 0) {
        out[0] = (sl[0] + sl[1] + sl[2] + sl[3]) * (1.f / (float)NROWS);
        out[1] = (sc[0] + sc[1] + sc[2] + sc[3]) * (1.f / (float)NROWS);
    }
}

extern "C" void kernel_launch(void* const* d_in, const int* in_sizes, int n_in,
                              void* d_out, int out_size, void* d_ws, size_t ws_size,
                              hipStream_t stream) {
    (void)in_sizes; (void)n_in; (void)out_size; (void)ws_size;
    const float* emb = (const float*)d_in[0];
    const float* lnw = (const float*)d_in[3];
    const float* lnb = (const float*)d_in[4];
    float* out = (float*)d_out;

    char* ws = (char*)d_ws;
    unsigned short* ck = (unsigned short*)ws;                      // 1 MB
    float* partsum = (float*)(ws + (size_t)N_SPK * D_DIM * 2);     // 2 KB

    ck_kernel<<<N_SPK, 256, 0, stream>>>(emb, lnw, ck);
    gemm_kernel<<<GRID, 512, 0, stream>>>(emb, ck, lnw, lnb, partsum);
    final_kernel<<<1, 256, 0, stream>>>(partsum, out);
}